// Round 20
// baseline (3166.397 us; speedup 1.0000x reference)
//
#include <hip/hip_runtime.h>
#include <math.h>

// Problem constants
static constexpr int cB = 32;
static constexpr int cT = 1024;
static constexpr int cH = 128;
static constexpr int cD = 256;   // 2H
static constexpr int cN = 2048;  // H*POOL
static constexpr int cM = cB * cT; // 32768

typedef __attribute__((ext_vector_type(8))) short short8;
typedef __attribute__((ext_vector_type(4))) float f32x4;

__device__ __forceinline__ ushort f2bf(float x) {
    union { float f; unsigned u; } v; v.f = x;
    unsigned r = v.u + 0x7FFF + ((v.u >> 16) & 1);   // RNE to bf16
    return (ushort)(r >> 16);
}
__device__ __forceinline__ float bf2f(ushort h) {
    union { float f; unsigned u; } v; v.u = ((unsigned)h) << 16;
    return v.f;
}

// async global->LDS, 16B per lane, wave-uniform LDS base + lane*16
__device__ __forceinline__ void gload_lds16(const ushort* g, ushort* l) {
    __builtin_amdgcn_global_load_lds(
        (const __attribute__((address_space(1))) unsigned int*)(const void*)g,
        (__attribute__((address_space(3))) unsigned int*)(void*)l,
        16, 0, 0);
}

// ---------------------------------------------------------------------------
// Fused m1 GEMM, counted-vmcnt pipeline, 4-blocks/CU occupancy variant:
//   m1[m][o] = max_{p<16}( sum_k U[m][k]*W1t[16o+p][k] + rterm[b][16o+p] )
// r19 plateau: every schedule ran 2 blocks/CU (64KB LDS) -> 8 lockstep waves,
// MfmaUtil pinned 22%. r18 body measures VGPR=100 -> fits a 128-reg budget,
// so (256,4) is spill-safe (r10's occupancy attempt failed only via spill).
// Here: 8 k-tiles of 32, dbuf LDS 2x8KB hi + 2x8KB lo = 32KB/block ->
// 4 blocks/CU = 16 waves/CU; blocks at different phases overlap stage drain
// with MFMA. Per tile: [s_barrier] -> issue stage(t+1) (4 gload_lds/wave) ->
// s_waitcnt vmcnt(4) (stage(t+1) stays in flight) -> s_barrier ->
// sched_barrier(0) -> { X(t) loads + ds_read + 48 MFMA }.
// Swapped mfma(W,X): pool = 3 in-lane fmax + shfl_xor(16,32). 3-term split.
// LDS swizzle (64B rows): chunk slot s of row r holds ck = s ^ ((r>>1)&3);
// read applies the same XOR -> 2-way (free).
// Grid 4096, bijective XCD-chunked remap.
// ---------------------------------------------------------------------------
__global__ __launch_bounds__(256, 4)
void m1_pipe_kernel(const ushort* __restrict__ Wth, const ushort* __restrict__ Wtl,
                    const ushort* __restrict__ Xh, const ushort* __restrict__ Xl,
                    const float* __restrict__ rterm,
                    float* __restrict__ out, ushort* __restrict__ outh,
                    ushort* __restrict__ outl)
{
    constexpr int K = 256;
    __shared__ __attribute__((aligned(16))) ushort sWh[2 * 4096];  // 2x8KB
    __shared__ __attribute__((aligned(16))) ushort sWl[2 * 4096];  // 2x8KB

    const int tid  = threadIdx.x;
    const int wave = tid >> 6;
    const int lane = tid & 63;
    const int l15  = lane & 15;
    const int lg   = lane >> 4;
    const int wn   = wave >> 1;         // n-half
    const int wm   = wave & 1;          // m-half

    const int wg  = blockIdx.x;
    const int lin = (wg & 7) * 512 + (wg >> 3);
    const int bx  = lin & 15;
    const int by  = lin >> 4;
    const int n0  = bx * 128;
    const int m0  = by * 128;
    const size_t ibase = (size_t)(m0 >> 10) * cN;

    float ivv[4][4];
    #pragma unroll
    for (int rf = 0; rf < 4; ++rf)
        #pragma unroll
        for (int r = 0; r < 4; ++r)
            ivv[rf][r] = rterm[ibase + n0 + wn * 64 + rf * 16 + lg * 4 + r];

    f32x4 acc[4][4];    // [rf(n)][cf(m)]
    #pragma unroll
    for (int rf = 0; rf < 4; ++rf)
        #pragma unroll
        for (int cf = 0; cf < 4; ++cf)
            acc[rf][cf] = (f32x4){0.f, 0.f, 0.f, 0.f};

    // staging geometry per 32-k tile: plane = 128 rows x 32 ushorts = 8KB =
    // 8 x 1KB instrs (16 rows each); lane -> row 16i+(lane>>2), slot lane&3;
    // global chunk ck = slot ^ ((row>>1)&3)  (both-sides swizzle, T21).
    const int st_r = lane >> 2;         // 0..15
    const int st_s = lane & 3;          // 0..3

    // ---- stage tile 0 -> buf 0 (4 gload_lds per wave) ---------------------
    #pragma unroll
    for (int j = 0; j < 2; ++j) {
        int i   = wave * 2 + j;             // 0..7
        int row = i * 16 + st_r;            // 0..127
        int ck  = st_s ^ ((row >> 1) & 3);
        size_t goff = (size_t)(n0 + row) * K + ck * 8;
        gload_lds16(Wth + goff, sWh + i * 512);
        gload_lds16(Wtl + goff, sWl + i * 512);
    }

    #pragma unroll
    for (int t = 0; t < 8; ++t) {
        const int cb = (t & 1) * 4096;          // compute buffer
        if (t > 0) __builtin_amdgcn_s_barrier();    // compute(t-1) retired
        if (t < 7) {
            const int nb = ((t + 1) & 1) * 4096;    // stage buffer
            const int kt = (t + 1) * 32;
            #pragma unroll
            for (int j = 0; j < 2; ++j) {
                int i   = wave * 2 + j;
                int row = i * 16 + st_r;
                int ck  = st_s ^ ((row >> 1) & 3);
                size_t goff = (size_t)(n0 + row) * K + kt + ck * 8;
                gload_lds16(Wth + goff, sWh + nb + i * 512);
                gload_lds16(Wtl + goff, sWl + nb + i * 512);
            }
            // stage(t) landed; stage(t+1)'s 4 ops stay in flight
            asm volatile("s_waitcnt vmcnt(4)" ::: "memory");
        } else {
            asm volatile("s_waitcnt vmcnt(0)" ::: "memory");
        }
        __builtin_amdgcn_s_barrier();
        __builtin_amdgcn_sched_barrier(0);

        // X fragments for this tile (just-in-time; 16 waves/CU hide latency)
        short8 xh_[4], xl_[4];
        #pragma unroll
        for (int cf = 0; cf < 4; ++cf) {
            size_t off = (size_t)(m0 + wm * 64 + cf * 16 + l15) * K
                       + t * 32 + lg * 8;
            xh_[cf] = *(const short8*)(Xh + off);
            xl_[cf] = *(const short8*)(Xl + off);
        }

        short8 w_h[4], w_l[4];
        #pragma unroll
        for (int rf = 0; rf < 4; ++rf) {
            int row  = wn * 64 + rf * 16 + l15;
            int adr  = cb + row * 32 + ((lg ^ ((row >> 1) & 3)) * 8);
            w_h[rf] = *(const short8*)(sWh + adr);
            w_l[rf] = *(const short8*)(sWl + adr);
        }
        #pragma unroll
        for (int rf = 0; rf < 4; ++rf)
            #pragma unroll
            for (int cf = 0; cf < 4; ++cf) {
                acc[rf][cf] = __builtin_amdgcn_mfma_f32_16x16x32_bf16(
                    w_h[rf], xh_[cf], acc[rf][cf], 0, 0, 0);
                acc[rf][cf] = __builtin_amdgcn_mfma_f32_16x16x32_bf16(
                    w_l[rf], xh_[cf], acc[rf][cf], 0, 0, 0);
                acc[rf][cf] = __builtin_amdgcn_mfma_f32_16x16x32_bf16(
                    w_h[rf], xl_[cf], acc[rf][cf], 0, 0, 0);
            }
    }

    // epilogue: in-lane pool over reg r + shfl over lg; lanes 0-15 store
    const int NP = 128;
    #pragma unroll
    for (int rf = 0; rf < 4; ++rf) {
        const int o2 = (n0 >> 4) + wn * 4 + rf;
        #pragma unroll
        for (int cf = 0; cf < 4; ++cf) {
            float v0 = acc[rf][cf][0] + ivv[rf][0];
            float v1 = acc[rf][cf][1] + ivv[rf][1];
            float v2 = acc[rf][cf][2] + ivv[rf][2];
            float v3 = acc[rf][cf][3] + ivv[rf][3];
            float mx = fmaxf(fmaxf(v0, v1), fmaxf(v2, v3));
            mx = fmaxf(mx, __shfl_xor(mx, 16));
            mx = fmaxf(mx, __shfl_xor(mx, 32));
            if (lane < 16) {
                int m = m0 + wm * 64 + cf * 16 + lane;
                size_t o = (size_t)m * NP + o2;
                out[o] = mx;
                ushort hb = f2bf(mx);
                outh[o] = hb;
                outl[o] = f2bf(mx - bf2f(hb));
            }
        }
    }
}

// ---------------------------------------------------------------------------
// m2 multi-subtile (K=128, S=4) — r13 kernel (unchanged).
// ---------------------------------------------------------------------------
__global__ __launch_bounds__(256, 2)
void mfma_pool_m2(const ushort* __restrict__ Wth, const ushort* __restrict__ Wtl,
                  const ushort* __restrict__ Xh, const ushort* __restrict__ Xl,
                  const float* __restrict__ bias, float* __restrict__ out)
{
    constexpr int K = 128, S = 4;
    __shared__ __attribute__((aligned(16))) ushort sWh[128 * 128];
    __shared__ __attribute__((aligned(16))) ushort sWl[128 * 128];

    const int tid  = threadIdx.x;
    const int wave = tid >> 6;
    const int lane = tid & 63;
    const int l15  = lane & 15;
    const int lg   = lane >> 4;
    const int wr   = wave >> 1;
    const int wc   = wave & 1;

    const int wg  = blockIdx.x;                  // grid 1024
    const int lin = (wg & 7) * 128 + (wg >> 3);
    const int bx  = lin & 15;
    const int by  = lin >> 4;
    const int n0  = bx * 128;

    float ivv[4][4];
    #pragma unroll
    for (int rf = 0; rf < 4; ++rf)
        #pragma unroll
        for (int r = 0; r < 4; ++r)
            ivv[rf][r] = bias[n0 + wr * 64 + rf * 16 + lg * 4 + r];

    const int st_row_lo = lane >> 4;
    const int st_slot   = lane & 15;
    #pragma unroll
    for (int j = 0; j < 8; ++j) {
        int i   = wave * 8 + j;
        int row = i * 4 + st_row_lo;
        int ck  = st_slot ^ (row & 7);
        size_t goff = (size_t)(n0 + row) * K + ck * 8;
        gload_lds16(Wth + goff, sWh + i * 512);
        gload_lds16(Wtl + goff, sWl + i * 512);
    }
    __syncthreads();

    const int NP = 128;
    #pragma unroll
    for (int s = 0; s < S; ++s) {
        const int m0 = by * 512 + s * 128;

        short8 xh_[16], xl_[16];
        #pragma unroll
        for (int cf = 0; cf < 4; ++cf)
            #pragma unroll
            for (int ks = 0; ks < 4; ++ks) {
                size_t off = (size_t)(m0 + wc * 64 + cf * 16 + l15) * K
                           + ks * 32 + lg * 8;
                xh_[cf * 4 + ks] = *(const short8*)(Xh + off);
                xl_[cf * 4 + ks] = *(const short8*)(Xl + off);
            }

        f32x4 acc[4][4];
        #pragma unroll
        for (int rf = 0; rf < 4; ++rf)
            #pragma unroll
            for (int cf = 0; cf < 4; ++cf)
                acc[rf][cf] = (f32x4){0.f, 0.f, 0.f, 0.f};

        #pragma unroll
        for (int ks = 0; ks < 4; ++ks) {
            short8 w_h[4], w_l[4];
            #pragma unroll
            for (int rf = 0; rf < 4; ++rf) {
                int row  = wr * 64 + rf * 16 + l15;
                int ck2  = ks * 4 + lg;
                int adr  = row * 128 + ((ck2 ^ (row & 7)) * 8);
                w_h[rf] = *(const short8*)(sWh + adr);
                w_l[rf] = *(const short8*)(sWl + adr);
            }
            #pragma unroll
            for (int rf = 0; rf < 4; ++rf)
                #pragma unroll
                for (int cf = 0; cf < 4; ++cf) {
                    acc[rf][cf] = __builtin_amdgcn_mfma_f32_16x16x32_bf16(
                        w_h[rf], xh_[cf * 4 + ks], acc[rf][cf], 0, 0, 0);
                    acc[rf][cf] = __builtin_amdgcn_mfma_f32_16x16x32_bf16(
                        w_l[rf], xh_[cf * 4 + ks], acc[rf][cf], 0, 0, 0);
                    acc[rf][cf] = __builtin_amdgcn_mfma_f32_16x16x32_bf16(
                        w_h[rf], xl_[cf * 4 + ks], acc[rf][cf], 0, 0, 0);
                }
        }

        #pragma unroll
        for (int rf = 0; rf < 4; ++rf) {
            const int o2 = (n0 >> 4) + wr * 4 + rf;
            #pragma unroll
            for (int cf = 0; cf < 4; ++cf) {
                float v0 = acc[rf][cf][0] + ivv[rf][0];
                float v1 = acc[rf][cf][1] + ivv[rf][1];
                float v2 = acc[rf][cf][2] + ivv[rf][2];
                float v3 = acc[rf][cf][3] + ivv[rf][3];
                float mx = fmaxf(fmaxf(v0, v1), fmaxf(v2, v3));
                mx = fmaxf(mx, __shfl_xor(mx, 16));
                mx = fmaxf(mx, __shfl_xor(mx, 32));
                if (lane < 16) {
                    int m = m0 + wc * 64 + cf * 16 + lane;
                    out[(size_t)m * NP + o2] = mx;
                }
            }
        }
    }
}

// ---------------------------------------------------------------------------
// Weight transpose + bf16 split: W[K x N] row-major -> Wt hi/lo [N][K]
// ---------------------------------------------------------------------------
__global__ void wsplit_kernel(const float* __restrict__ W, int K, int N,
                              ushort* __restrict__ th, ushort* __restrict__ tl)
{
    int idx = blockIdx.x * 256 + threadIdx.x;
    if (idx >= K * N) return;
    int k = idx / N, n = idx - k * N;      // coalesced read
    float x = W[idx];
    ushort h = f2bf(x);
    th[(size_t)n * K + k] = h;
    tl[(size_t)n * K + k] = f2bf(x - bf2f(h));
}

// ---------------------------------------------------------------------------
// U split: U fp32 [M][256] -> Uh/Ul bf16 same layout
// ---------------------------------------------------------------------------
__global__ void usplit_kernel(const float* __restrict__ U,
                              ushort* __restrict__ uh, ushort* __restrict__ ul)
{
    int idx = blockIdx.x * 256 + threadIdx.x;   // cM*cD threads
    float x = U[idx];
    ushort h = f2bf(x);
    uh[idx] = h;
    ul[idx] = f2bf(x - bf2f(h));
}

// ---------------------------------------------------------------------------
// r[b][j] = tanh( concat([h,us,ue])[b] . WDw[:,j] + WDb[j] )
// ---------------------------------------------------------------------------
__global__ void r_kernel(const float* __restrict__ h, const float* __restrict__ us,
                         const float* __restrict__ ue,
                         const float* __restrict__ WDw, const float* __restrict__ WDb,
                         float* __restrict__ r)
{
    int b = blockIdx.x;
    int j = threadIdx.x;  // 128 threads
    __shared__ float x[640];
    x[j]       = h[b * cH + j];
    x[128 + j] = us[b * cD + j];
    x[256 + j] = us[b * cD + 128 + j];
    x[384 + j] = ue[b * cD + j];
    x[512 + j] = ue[b * cD + 128 + j];
    __syncthreads();
    float s = WDb[j];
    for (int k = 0; k < 640; ++k) s = fmaf(x[k], WDw[(size_t)k * cH + j], s);
    r[b * cH + j] = tanhf(s);
}

// ---------------------------------------------------------------------------
// rterm[b][n] = r[b] . W1r[:,n] + W1b[n]    (W1r = rows 256..383 of W1w)
// ---------------------------------------------------------------------------
__global__ void rterm_kernel(const float* __restrict__ r, const float* __restrict__ W1r,
                             const float* __restrict__ W1b, float* __restrict__ rterm)
{
    int b = blockIdx.y;
    int n = blockIdx.x * 256 + threadIdx.x;  // grid (8,32)
    __shared__ float rs[128];
    if (threadIdx.x < 128) rs[threadIdx.x] = r[b * cH + threadIdx.x];
    __syncthreads();
    float s = W1b[n];
    for (int k = 0; k < 128; ++k) s = fmaf(rs[k], W1r[(size_t)k * cN + n], s);
    rterm[(size_t)b * cN + n] = s;
}

// ---------------------------------------------------------------------------
// score[m] = max_p( concat([m1,m2])[m] . W3w[:,p] + W3b[p] ) -> ent region
// ---------------------------------------------------------------------------
__global__ __launch_bounds__(256)
void score_kernel(const float* __restrict__ m1, const float* __restrict__ m2,
                  const float* __restrict__ W3w, const float* __restrict__ W3b,
                  float* __restrict__ ent)
{
    __shared__ float xs[16][257];
    __shared__ float wsh[256 * 16];
    int tid = threadIdx.x;
    int m0 = blockIdx.x * 16;
    #pragma unroll
    for (int q = 0; q < 16; ++q) wsh[tid + q * 256] = W3w[tid + q * 256];
    #pragma unroll
    for (int q = 0; q < 8; ++q) {
        int f = tid + q * 256;
        int rl = f >> 7, col = f & 127;
        xs[rl][col]       = m1[(size_t)(m0 + rl) * cH + col];
        xs[rl][128 + col] = m2[(size_t)(m0 + rl) * cH + col];
    }
    __syncthreads();
    int rl = tid >> 4, p = tid & 15;
    float s = W3b[p];
    for (int k = 0; k < 256; ++k) s = fmaf(xs[rl][k], wsh[k * 16 + p], s);
    #pragma unroll
    for (int off = 8; off; off >>= 1) s = fmaxf(s, __shfl_xor(s, off));
    if (p == 0) ent[m0 + rl] = s;
}

// ---------------------------------------------------------------------------
// argmax over T per batch (first-occurrence ties), write float index,
// gather U row into us/ue
// ---------------------------------------------------------------------------
__global__ void argmax_kernel(const float* __restrict__ sc, const float* __restrict__ U,
                              float* __restrict__ uvec, float* __restrict__ outidx)
{
    int b = blockIdx.x;
    int tid = threadIdx.x;  // 256
    float bv = -3.4e38f;
    int bi = 0x7fffffff;
    for (int t = tid; t < cT; t += 256) {
        float v = sc[b * cT + t];
        if (v > bv || (v == bv && t < bi)) { bv = v; bi = t; }
    }
    __shared__ float vs[256];
    __shared__ int   is[256];
    vs[tid] = bv; is[tid] = bi;
    __syncthreads();
    for (int s = 128; s > 0; s >>= 1) {
        if (tid < s) {
            if (vs[tid + s] > vs[tid] ||
                (vs[tid + s] == vs[tid] && is[tid + s] < is[tid])) {
                vs[tid] = vs[tid + s];
                is[tid] = is[tid + s];
            }
        }
        __syncthreads();
    }
    int best = is[0];
    if (tid == 0) outidx[b] = (float)best;
    uvec[b * cD + tid % cD] = U[((size_t)b * cT + best) * cD + (tid % cD)];
}

// ---------------------------------------------------------------------------
// LSTM cell — wave-per-(batch, j) (r19, verified fast).
// ---------------------------------------------------------------------------
__global__ __launch_bounds__(256)
void lstm_kernel(const float* __restrict__ us, const float* __restrict__ ue,
                 float* __restrict__ h, float* __restrict__ c,
                 const float* __restrict__ wih, const float* __restrict__ whh,
                 const float* __restrict__ bih, const float* __restrict__ bhh)
{
    const int wid  = blockIdx.x * 4 + (threadIdx.x >> 6);  // 0..4095
    const int lane = threadIdx.x & 63;
    const int b    = wid >> 7;          // batch
    const int j    = wid & 127;         // hidden index

    float xv[8], hv[2];
    #pragma unroll
    for (int i = 0; i < 8; ++i) {
        int k = lane + 64 * i;
        xv[i] = (k < 256) ? us[b * cD + k] : ue[b * cD + (k - 256)];
    }
    #pragma unroll
    for (int i = 0; i < 2; ++i)
        hv[i] = h[b * cH + lane + 64 * i];

    float g4[4];
    #pragma unroll
    for (int gi = 0; gi < 4; ++gi) {
        const int row = gi * 128 + j;
        const float* wr  = wih + (size_t)row * 512;
        const float* wr2 = whh + (size_t)row * 128;
        float s = 0.f;
        #pragma unroll
        for (int i = 0; i < 8; ++i) s = fmaf(xv[i], wr[lane + 64 * i], s);
        #pragma unroll
        for (int i = 0; i < 2; ++i) s = fmaf(hv[i], wr2[lane + 64 * i], s);
        #pragma unroll
        for (int off = 32; off; off >>= 1) s += __shfl_xor(s, off);
        g4[gi] = s + bih[row] + bhh[row];
    }

    if (lane == 0) {
        float i_ = 1.f / (1.f + expf(-g4[0]));
        float f_ = 1.f / (1.f + expf(-g4[1]));
        float g_ = tanhf(g4[2]);
        float o_ = 1.f / (1.f + expf(-g4[3]));
        float c2 = f_ * c[b * cH + j] + i_ * g_;
        float h2 = o_ * tanhf(c2);
        c[b * cH + j] = c2;
        h[b * cH + j] = h2;
    }
}

__global__ void init_kernel(const float* __restrict__ U, float* __restrict__ us,
                            float* __restrict__ ue, float* __restrict__ h,
                            float* __restrict__ c)
{
    int i = blockIdx.x * 256 + threadIdx.x;  // 8192 threads
    if (i < cB * cD) {
        int b = i >> 8, d = i & 255;
        us[i] = U[((size_t)b * cT + 0) * cD + d];
        ue[i] = U[((size_t)b * cT + 1) * cD + d];
    }
    if (i < cB * cH) { h[i] = 0.f; c[i] = 0.f; }
}

// ---------------------------------------------------------------------------
extern "C" void kernel_launch(void* const* d_in, const int* in_sizes, int n_in,
                              void* d_out, int out_size, void* d_ws, size_t ws_size,
                              hipStream_t stream)
{
    const float* U = (const float*)d_in[0];
    const float* WD_w[2] = {(const float*)d_in[1], (const float*)d_in[9]};
    const float* WD_b[2] = {(const float*)d_in[2], (const float*)d_in[10]};
    const float* W1_w[2] = {(const float*)d_in[3], (const float*)d_in[11]};
    const float* W1_b[2] = {(const float*)d_in[4], (const float*)d_in[12]};
    const float* W2_w[2] = {(const float*)d_in[5], (const float*)d_in[13]};
    const float* W2_b[2] = {(const float*)d_in[6], (const float*)d_in[14]};
    const float* W3_w[2] = {(const float*)d_in[7], (const float*)d_in[15]};
    const float* W3_b[2] = {(const float*)d_in[8], (const float*)d_in[16]};
    const float* wih = (const float*)d_in[17];
    const float* whh = (const float*)d_in[18];
    const float* bih = (const float*)d_in[19];
    const float* bhh = (const float*)d_in[20];

    float* ws = (float*)d_ws;
    float* m1 = ws;                               // 4M floats
    float* m2 = m1 + (size_t)cM * cH;             // 4M
    float* us = m2 + (size_t)cM * cH;
    float* ue = us + cB * cD;
    float* h  = ue + cB * cD;
    float* c  = h + cB * cH;
    float* r  = c + cB * cH;
    float* rterm = r + cB * cH;                   // 64K
    float* cur = rterm + (size_t)cB * cN;

    ushort* m1h = (ushort*)cur;                   cur += (size_t)cM * cH / 2;
    ushort* m1l = (ushort*)cur;                   cur += (size_t)cM * cH / 2;
    ushort* Uh  = (ushort*)cur;                   cur += (size_t)cM * cD / 2;
    ushort* Ul  = (ushort*)cur;                   cur += (size_t)cM * cD / 2;
    ushort* W1th[2], *W1tl[2], *W2th[2], *W2tl[2];
    for (int sd = 0; sd < 2; ++sd) {
        W1th[sd] = (ushort*)cur; cur += (size_t)cN * cD / 2;   // [2048][256]
        W1tl[sd] = (ushort*)cur; cur += (size_t)cN * cD / 2;
        W2th[sd] = (ushort*)cur; cur += (size_t)cN * cH / 2;   // [2048][128]
        W2tl[sd] = (ushort*)cur; cur += (size_t)cN * cH / 2;
    }

    float* outf = (float*)d_out;

    init_kernel<<<32, 256, 0, stream>>>(U, us, ue, h, c);
    usplit_kernel<<<(cM * cD) / 256, 256, 0, stream>>>(U, Uh, Ul);
    for (int sd = 0; sd < 2; ++sd) {
        wsplit_kernel<<<(cD * cN) / 256, 256, 0, stream>>>(
            W1_w[sd], cD, cN, W1th[sd], W1tl[sd]);     // first 256 rows of W1
        wsplit_kernel<<<(cH * cN) / 256, 256, 0, stream>>>(
            W2_w[sd], cH, cN, W2th[sd], W2tl[sd]);
    }

    const int ggrid = (cN / 128) * (cM / 128);   // 4096
    for (int it = 0; it < 4; ++it) {
        for (int sd = 0; sd < 2; ++sd) {
            r_kernel<<<32, 128, 0, stream>>>(h, us, ue, WD_w[sd], WD_b[sd], r);
            rterm_kernel<<<dim3(8, 32), 256, 0, stream>>>(
                r, W1_w[sd] + (size_t)256 * cN, W1_b[sd], rterm);
            // m1 = pool(U @ W1[0:256] + rterm) — counted-vmcnt, 4 blk/CU
            m1_pipe_kernel<<<ggrid, 256, 0, stream>>>(
                W1th[sd], W1tl[sd], Uh, Ul, rterm, m1, m1h, m1l);
            // m2 = pool(m1 @ W2 + b2) — r13 multi-subtile
            mfma_pool_m2<<<1024, 256, 0, stream>>>(
                W2th[sd], W2tl[sd], m1h, m1l, W2_b[sd], m2);
            float* ent = outf + 64 + (size_t)(it * 2 + sd) * cB * cT;
            score_kernel<<<2048, 256, 0, stream>>>(m1, m2, W3_w[sd], W3_b[sd], ent);
            argmax_kernel<<<32, 256, 0, stream>>>(ent, U, sd ? ue : us,
                                                  outf + (sd ? 32 : 0));
        }
        lstm_kernel<<<1024, 256, 0, stream>>>(us, ue, h, c, wih, whh, bih, bhh);
    }
}

// Round 21
// 2406.008 us; speedup vs baseline: 1.3160x; 1.3160x over previous
//
#include <hip/hip_runtime.h>
#include <math.h>

// Problem constants
static constexpr int cB = 32;
static constexpr int cT = 1024;
static constexpr int cH = 128;
static constexpr int cD = 256;   // 2H
static constexpr int cN = 2048;  // H*POOL
static constexpr int cM = cB * cT; // 32768

typedef __attribute__((ext_vector_type(8))) short short8;
typedef __attribute__((ext_vector_type(4))) float f32x4;

__device__ __forceinline__ ushort f2bf(float x) {
    union { float f; unsigned u; } v; v.f = x;
    unsigned r = v.u + 0x7FFF + ((v.u >> 16) & 1);   // RNE to bf16
    return (ushort)(r >> 16);
}
__device__ __forceinline__ float bf2f(ushort h) {
    union { float f; unsigned u; } v; v.u = ((unsigned)h) << 16;
    return v.f;
}

// async global->LDS, 16B per lane, wave-uniform LDS base + lane*16
__device__ __forceinline__ void gload_lds16(const ushort* g, ushort* l) {
    __builtin_amdgcn_global_load_lds(
        (const __attribute__((address_space(1))) unsigned int*)(const void*)g,
        (__attribute__((address_space(3))) unsigned int*)(void*)l,
        16, 0, 0);
}

// ---------------------------------------------------------------------------
// Fused m1 GEMM with counted-vmcnt pipeline (r18/r19 verified best config):
//   m1[m][o] = max_{p<16}( sum_k U[m][k]*W1t[16o+p][k] + rterm[b][16o+p] )
// K=256, 4 k-tiles of 64, double-buffered W in LDS (2x16KB hi + 2x16KB lo),
// 2 blocks/CU. Per tile: [s_barrier] -> issue stage(t+1) (8 gload_lds/wave)
// -> s_waitcnt vmcnt(8) (stage(t+1) stays in flight) -> s_barrier ->
// sched_barrier(0) -> { X(t) loads + ds_read + 96 MFMA }.
// Swapped mfma(W,X): pool = 3 in-lane fmax + shfl_xor(16,32). 3-term split
// wh*xh + wl*xh + wh*xl, fp32 MFMA accumulate (argmax-exact).
// Grid 4096, bijective XCD-chunked remap. LDS swizzle (128B rows): chunk
// slot s of row r holds ck = s^(r&7) (source-side); read applies same XOR.
// NOTE (r20): do NOT raise launch_bounds occupancy — (256,4) spills the
// accumulator (VGPR 64, scratch 400MB) and 2x occupancy LOWERED MfmaUtil.
// ---------------------------------------------------------------------------
__global__ __launch_bounds__(256, 2)
void m1_pipe_kernel(const ushort* __restrict__ Wth, const ushort* __restrict__ Wtl,
                    const ushort* __restrict__ Xh, const ushort* __restrict__ Xl,
                    const float* __restrict__ rterm,
                    float* __restrict__ out, ushort* __restrict__ outh,
                    ushort* __restrict__ outl)
{
    constexpr int K = 256;
    __shared__ __attribute__((aligned(16))) ushort sWh[2 * 8192];  // 2x16KB
    __shared__ __attribute__((aligned(16))) ushort sWl[2 * 8192];  // 2x16KB

    const int tid  = threadIdx.x;
    const int wave = tid >> 6;
    const int lane = tid & 63;
    const int l15  = lane & 15;
    const int lg   = lane >> 4;
    const int wn   = wave >> 1;         // n-half
    const int wm   = wave & 1;          // m-half

    const int wg  = blockIdx.x;
    const int lin = (wg & 7) * 512 + (wg >> 3);
    const int bx  = lin & 15;
    const int by  = lin >> 4;
    const int n0  = bx * 128;
    const int m0  = by * 128;
    const size_t ibase = (size_t)(m0 >> 10) * cN;

    float ivv[4][4];
    #pragma unroll
    for (int rf = 0; rf < 4; ++rf)
        #pragma unroll
        for (int r = 0; r < 4; ++r)
            ivv[rf][r] = rterm[ibase + n0 + wn * 64 + rf * 16 + lg * 4 + r];

    f32x4 acc[4][4];    // [rf(n)][cf(m)]
    #pragma unroll
    for (int rf = 0; rf < 4; ++rf)
        #pragma unroll
        for (int cf = 0; cf < 4; ++cf)
            acc[rf][cf] = (f32x4){0.f, 0.f, 0.f, 0.f};

    const int st_r = lane >> 3;         // 0..7
    const int st_s = lane & 7;          // 0..7

    // ---- stage tile 0 -> buf 0 (8 gload_lds per wave) ---------------------
    #pragma unroll
    for (int j = 0; j < 4; ++j) {
        int i   = wave * 4 + j;             // 0..15
        int row = i * 8 + st_r;             // 0..127
        int ck  = st_s ^ (row & 7);
        size_t goff = (size_t)(n0 + row) * K + ck * 8;
        gload_lds16(Wth + goff, sWh + i * 512);
        gload_lds16(Wtl + goff, sWl + i * 512);
    }

    #pragma unroll
    for (int t = 0; t < 4; ++t) {
        const int cb = (t & 1) * 8192;          // compute buffer
        if (t > 0) __builtin_amdgcn_s_barrier();    // compute(t-1) retired
        if (t < 3) {
            const int nb = ((t + 1) & 1) * 8192;    // stage buffer
            const int kt = (t + 1) * 64;
            #pragma unroll
            for (int j = 0; j < 4; ++j) {
                int i   = wave * 4 + j;
                int row = i * 8 + st_r;
                int ck  = st_s ^ (row & 7);
                size_t goff = (size_t)(n0 + row) * K + kt + ck * 8;
                gload_lds16(Wth + goff, sWh + nb + i * 512);
                gload_lds16(Wtl + goff, sWl + nb + i * 512);
            }
            // stage(t) landed; stage(t+1)'s 8 ops stay in flight
            asm volatile("s_waitcnt vmcnt(8)" ::: "memory");
        } else {
            asm volatile("s_waitcnt vmcnt(0)" ::: "memory");
        }
        __builtin_amdgcn_s_barrier();
        __builtin_amdgcn_sched_barrier(0);

        // X fragments for this tile (just-in-time; TLP hides L2 latency)
        short8 xh_[8], xl_[8];      // [cf*2+ks]
        #pragma unroll
        for (int cf = 0; cf < 4; ++cf)
            #pragma unroll
            for (int ks = 0; ks < 2; ++ks) {
                size_t off = (size_t)(m0 + wm * 64 + cf * 16 + l15) * K
                           + t * 64 + ks * 32 + lg * 8;
                xh_[cf * 2 + ks] = *(const short8*)(Xh + off);
                xl_[cf * 2 + ks] = *(const short8*)(Xl + off);
            }

        #pragma unroll
        for (int ks = 0; ks < 2; ++ks) {
            short8 w_h[4], w_l[4];
            #pragma unroll
            for (int rf = 0; rf < 4; ++rf) {
                int row  = wn * 64 + rf * 16 + l15;
                int ck2  = ks * 4 + lg;             // 0..7
                int adr  = cb + row * 64 + ((ck2 ^ (row & 7)) * 8);
                w_h[rf] = *(const short8*)(sWh + adr);
                w_l[rf] = *(const short8*)(sWl + adr);
            }
            #pragma unroll
            for (int rf = 0; rf < 4; ++rf)
                #pragma unroll
                for (int cf = 0; cf < 4; ++cf) {
                    acc[rf][cf] = __builtin_amdgcn_mfma_f32_16x16x32_bf16(
                        w_h[rf], xh_[cf * 2 + ks], acc[rf][cf], 0, 0, 0);
                    acc[rf][cf] = __builtin_amdgcn_mfma_f32_16x16x32_bf16(
                        w_l[rf], xh_[cf * 2 + ks], acc[rf][cf], 0, 0, 0);
                    acc[rf][cf] = __builtin_amdgcn_mfma_f32_16x16x32_bf16(
                        w_h[rf], xl_[cf * 2 + ks], acc[rf][cf], 0, 0, 0);
                }
        }
    }

    // epilogue: in-lane pool over reg r + shfl over lg; lanes 0-15 store
    const int NP = 128;
    #pragma unroll
    for (int rf = 0; rf < 4; ++rf) {
        const int o2 = (n0 >> 4) + wn * 4 + rf;
        #pragma unroll
        for (int cf = 0; cf < 4; ++cf) {
            float v0 = acc[rf][cf][0] + ivv[rf][0];
            float v1 = acc[rf][cf][1] + ivv[rf][1];
            float v2 = acc[rf][cf][2] + ivv[rf][2];
            float v3 = acc[rf][cf][3] + ivv[rf][3];
            float mx = fmaxf(fmaxf(v0, v1), fmaxf(v2, v3));
            mx = fmaxf(mx, __shfl_xor(mx, 16));
            mx = fmaxf(mx, __shfl_xor(mx, 32));
            if (lane < 16) {
                int m = m0 + wm * 64 + cf * 16 + lane;
                size_t o = (size_t)m * NP + o2;
                out[o] = mx;
                ushort hb = f2bf(mx);
                outh[o] = hb;
                outl[o] = f2bf(mx - bf2f(hb));
            }
        }
    }
}

// ---------------------------------------------------------------------------
// m2 multi-subtile (K=128, S=4) — r13 kernel (verified).
// ---------------------------------------------------------------------------
__global__ __launch_bounds__(256, 2)
void mfma_pool_m2(const ushort* __restrict__ Wth, const ushort* __restrict__ Wtl,
                  const ushort* __restrict__ Xh, const ushort* __restrict__ Xl,
                  const float* __restrict__ bias, float* __restrict__ out)
{
    constexpr int K = 128, S = 4;
    __shared__ __attribute__((aligned(16))) ushort sWh[128 * 128];
    __shared__ __attribute__((aligned(16))) ushort sWl[128 * 128];

    const int tid  = threadIdx.x;
    const int wave = tid >> 6;
    const int lane = tid & 63;
    const int l15  = lane & 15;
    const int lg   = lane >> 4;
    const int wr   = wave >> 1;
    const int wc   = wave & 1;

    const int wg  = blockIdx.x;                  // grid 1024
    const int lin = (wg & 7) * 128 + (wg >> 3);
    const int bx  = lin & 15;
    const int by  = lin >> 4;
    const int n0  = bx * 128;

    float ivv[4][4];
    #pragma unroll
    for (int rf = 0; rf < 4; ++rf)
        #pragma unroll
        for (int r = 0; r < 4; ++r)
            ivv[rf][r] = bias[n0 + wr * 64 + rf * 16 + lg * 4 + r];

    const int st_row_lo = lane >> 4;
    const int st_slot   = lane & 15;
    #pragma unroll
    for (int j = 0; j < 8; ++j) {
        int i   = wave * 8 + j;
        int row = i * 4 + st_row_lo;
        int ck  = st_slot ^ (row & 7);
        size_t goff = (size_t)(n0 + row) * K + ck * 8;
        gload_lds16(Wth + goff, sWh + i * 512);
        gload_lds16(Wtl + goff, sWl + i * 512);
    }
    __syncthreads();

    const int NP = 128;
    #pragma unroll
    for (int s = 0; s < S; ++s) {
        const int m0 = by * 512 + s * 128;

        short8 xh_[16], xl_[16];
        #pragma unroll
        for (int cf = 0; cf < 4; ++cf)
            #pragma unroll
            for (int ks = 0; ks < 4; ++ks) {
                size_t off = (size_t)(m0 + wc * 64 + cf * 16 + l15) * K
                           + ks * 32 + lg * 8;
                xh_[cf * 4 + ks] = *(const short8*)(Xh + off);
                xl_[cf * 4 + ks] = *(const short8*)(Xl + off);
            }

        f32x4 acc[4][4];
        #pragma unroll
        for (int rf = 0; rf < 4; ++rf)
            #pragma unroll
            for (int cf = 0; cf < 4; ++cf)
                acc[rf][cf] = (f32x4){0.f, 0.f, 0.f, 0.f};

        #pragma unroll
        for (int ks = 0; ks < 4; ++ks) {
            short8 w_h[4], w_l[4];
            #pragma unroll
            for (int rf = 0; rf < 4; ++rf) {
                int row  = wr * 64 + rf * 16 + l15;
                int ck2  = ks * 4 + lg;
                int adr  = row * 128 + ((ck2 ^ (row & 7)) * 8);
                w_h[rf] = *(const short8*)(sWh + adr);
                w_l[rf] = *(const short8*)(sWl + adr);
            }
            #pragma unroll
            for (int rf = 0; rf < 4; ++rf)
                #pragma unroll
                for (int cf = 0; cf < 4; ++cf) {
                    acc[rf][cf] = __builtin_amdgcn_mfma_f32_16x16x32_bf16(
                        w_h[rf], xh_[cf * 4 + ks], acc[rf][cf], 0, 0, 0);
                    acc[rf][cf] = __builtin_amdgcn_mfma_f32_16x16x32_bf16(
                        w_l[rf], xh_[cf * 4 + ks], acc[rf][cf], 0, 0, 0);
                    acc[rf][cf] = __builtin_amdgcn_mfma_f32_16x16x32_bf16(
                        w_h[rf], xl_[cf * 4 + ks], acc[rf][cf], 0, 0, 0);
                }
        }

        #pragma unroll
        for (int rf = 0; rf < 4; ++rf) {
            const int o2 = (n0 >> 4) + wr * 4 + rf;
            #pragma unroll
            for (int cf = 0; cf < 4; ++cf) {
                float v0 = acc[rf][cf][0] + ivv[rf][0];
                float v1 = acc[rf][cf][1] + ivv[rf][1];
                float v2 = acc[rf][cf][2] + ivv[rf][2];
                float v3 = acc[rf][cf][3] + ivv[rf][3];
                float mx = fmaxf(fmaxf(v0, v1), fmaxf(v2, v3));
                mx = fmaxf(mx, __shfl_xor(mx, 16));
                mx = fmaxf(mx, __shfl_xor(mx, 32));
                if (lane < 16) {
                    int m = m0 + wc * 64 + cf * 16 + lane;
                    out[(size_t)m * NP + o2] = mx;
                }
            }
        }
    }
}

// ---------------------------------------------------------------------------
// Weight transpose + bf16 split: W[K x N] row-major -> Wt hi/lo [N][K]
// ---------------------------------------------------------------------------
__global__ void wsplit_kernel(const float* __restrict__ W, int K, int N,
                              ushort* __restrict__ th, ushort* __restrict__ tl)
{
    int idx = blockIdx.x * 256 + threadIdx.x;
    if (idx >= K * N) return;
    int k = idx / N, n = idx - k * N;      // coalesced read
    float x = W[idx];
    ushort h = f2bf(x);
    th[(size_t)n * K + k] = h;
    tl[(size_t)n * K + k] = f2bf(x - bf2f(h));
}

// ---------------------------------------------------------------------------
// U split: U fp32 [M][256] -> Uh/Ul bf16 same layout
// ---------------------------------------------------------------------------
__global__ void usplit_kernel(const float* __restrict__ U,
                              ushort* __restrict__ uh, ushort* __restrict__ ul)
{
    int idx = blockIdx.x * 256 + threadIdx.x;   // cM*cD threads
    float x = U[idx];
    ushort h = f2bf(x);
    uh[idx] = h;
    ul[idx] = f2bf(x - bf2f(h));
}

// ---------------------------------------------------------------------------
// r[b][j] = tanh( concat([h,us,ue])[b] . WDw[:,j] + WDb[j] )
// ---------------------------------------------------------------------------
__global__ void r_kernel(const float* __restrict__ h, const float* __restrict__ us,
                         const float* __restrict__ ue,
                         const float* __restrict__ WDw, const float* __restrict__ WDb,
                         float* __restrict__ r)
{
    int b = blockIdx.x;
    int j = threadIdx.x;  // 128 threads
    __shared__ float x[640];
    x[j]       = h[b * cH + j];
    x[128 + j] = us[b * cD + j];
    x[256 + j] = us[b * cD + 128 + j];
    x[384 + j] = ue[b * cD + j];
    x[512 + j] = ue[b * cD + 128 + j];
    __syncthreads();
    float s = WDb[j];
    for (int k = 0; k < 640; ++k) s = fmaf(x[k], WDw[(size_t)k * cH + j], s);
    r[b * cH + j] = tanhf(s);
}

// ---------------------------------------------------------------------------
// rterm[b][n] = r[b] . W1r[:,n] + W1b[n]    (W1r = rows 256..383 of W1w)
// ---------------------------------------------------------------------------
__global__ void rterm_kernel(const float* __restrict__ r, const float* __restrict__ W1r,
                             const float* __restrict__ W1b, float* __restrict__ rterm)
{
    int b = blockIdx.y;
    int n = blockIdx.x * 256 + threadIdx.x;  // grid (8,32)
    __shared__ float rs[128];
    if (threadIdx.x < 128) rs[threadIdx.x] = r[b * cH + threadIdx.x];
    __syncthreads();
    float s = W1b[n];
    for (int k = 0; k < 128; ++k) s = fmaf(rs[k], W1r[(size_t)k * cN + n], s);
    rterm[(size_t)b * cN + n] = s;
}

// ---------------------------------------------------------------------------
// score[m] = max_p( concat([m1,m2])[m] . W3w[:,p] + W3b[p] ) -> ent region
// ---------------------------------------------------------------------------
__global__ __launch_bounds__(256)
void score_kernel(const float* __restrict__ m1, const float* __restrict__ m2,
                  const float* __restrict__ W3w, const float* __restrict__ W3b,
                  float* __restrict__ ent)
{
    __shared__ float xs[16][257];
    __shared__ float wsh[256 * 16];
    int tid = threadIdx.x;
    int m0 = blockIdx.x * 16;
    #pragma unroll
    for (int q = 0; q < 16; ++q) wsh[tid + q * 256] = W3w[tid + q * 256];
    #pragma unroll
    for (int q = 0; q < 8; ++q) {
        int f = tid + q * 256;
        int rl = f >> 7, col = f & 127;
        xs[rl][col]       = m1[(size_t)(m0 + rl) * cH + col];
        xs[rl][128 + col] = m2[(size_t)(m0 + rl) * cH + col];
    }
    __syncthreads();
    int rl = tid >> 4, p = tid & 15;
    float s = W3b[p];
    for (int k = 0; k < 256; ++k) s = fmaf(xs[rl][k], wsh[k * 16 + p], s);
    #pragma unroll
    for (int off = 8; off; off >>= 1) s = fmaxf(s, __shfl_xor(s, off));
    if (p == 0) ent[m0 + rl] = s;
}

// ---------------------------------------------------------------------------
// argmax over T per batch (first-occurrence ties), write float index,
// gather U row into us/ue
// ---------------------------------------------------------------------------
__global__ void argmax_kernel(const float* __restrict__ sc, const float* __restrict__ U,
                              float* __restrict__ uvec, float* __restrict__ outidx)
{
    int b = blockIdx.x;
    int tid = threadIdx.x;  // 256
    float bv = -3.4e38f;
    int bi = 0x7fffffff;
    for (int t = tid; t < cT; t += 256) {
        float v = sc[b * cT + t];
        if (v > bv || (v == bv && t < bi)) { bv = v; bi = t; }
    }
    __shared__ float vs[256];
    __shared__ int   is[256];
    vs[tid] = bv; is[tid] = bi;
    __syncthreads();
    for (int s = 128; s > 0; s >>= 1) {
        if (tid < s) {
            if (vs[tid + s] > vs[tid] ||
                (vs[tid + s] == vs[tid] && is[tid + s] < is[tid])) {
                vs[tid] = vs[tid + s];
                is[tid] = is[tid + s];
            }
        }
        __syncthreads();
    }
    int best = is[0];
    if (tid == 0) outidx[b] = (float)best;
    uvec[b * cD + tid % cD] = U[((size_t)b * cT + best) * cD + (tid % cD)];
}

// ---------------------------------------------------------------------------
// LSTM cell — wave-per-(batch, j) (r19, verified fast).
// ---------------------------------------------------------------------------
__global__ __launch_bounds__(256)
void lstm_kernel(const float* __restrict__ us, const float* __restrict__ ue,
                 float* __restrict__ h, float* __restrict__ c,
                 const float* __restrict__ wih, const float* __restrict__ whh,
                 const float* __restrict__ bih, const float* __restrict__ bhh)
{
    const int wid  = blockIdx.x * 4 + (threadIdx.x >> 6);  // 0..4095
    const int lane = threadIdx.x & 63;
    const int b    = wid >> 7;          // batch
    const int j    = wid & 127;         // hidden index

    float xv[8], hv[2];
    #pragma unroll
    for (int i = 0; i < 8; ++i) {
        int k = lane + 64 * i;
        xv[i] = (k < 256) ? us[b * cD + k] : ue[b * cD + (k - 256)];
    }
    #pragma unroll
    for (int i = 0; i < 2; ++i)
        hv[i] = h[b * cH + lane + 64 * i];

    float g4[4];
    #pragma unroll
    for (int gi = 0; gi < 4; ++gi) {
        const int row = gi * 128 + j;
        const float* wr  = wih + (size_t)row * 512;
        const float* wr2 = whh + (size_t)row * 128;
        float s = 0.f;
        #pragma unroll
        for (int i = 0; i < 8; ++i) s = fmaf(xv[i], wr[lane + 64 * i], s);
        #pragma unroll
        for (int i = 0; i < 2; ++i) s = fmaf(hv[i], wr2[lane + 64 * i], s);
        #pragma unroll
        for (int off = 32; off; off >>= 1) s += __shfl_xor(s, off);
        g4[gi] = s + bih[row] + bhh[row];
    }

    if (lane == 0) {
        float i_ = 1.f / (1.f + expf(-g4[0]));
        float f_ = 1.f / (1.f + expf(-g4[1]));
        float g_ = tanhf(g4[2]);
        float o_ = 1.f / (1.f + expf(-g4[3]));
        float c2 = f_ * c[b * cH + j] + i_ * g_;
        float h2 = o_ * tanhf(c2);
        c[b * cH + j] = c2;
        h[b * cH + j] = h2;
    }
}

__global__ void init_kernel(const float* __restrict__ U, float* __restrict__ us,
                            float* __restrict__ ue, float* __restrict__ h,
                            float* __restrict__ c)
{
    int i = blockIdx.x * 256 + threadIdx.x;  // 8192 threads
    if (i < cB * cD) {
        int b = i >> 8, d = i & 255;
        us[i] = U[((size_t)b * cT + 0) * cD + d];
        ue[i] = U[((size_t)b * cT + 1) * cD + d];
    }
    if (i < cB * cH) { h[i] = 0.f; c[i] = 0.f; }
}

// ---------------------------------------------------------------------------
extern "C" void kernel_launch(void* const* d_in, const int* in_sizes, int n_in,
                              void* d_out, int out_size, void* d_ws, size_t ws_size,
                              hipStream_t stream)
{
    const float* U = (const float*)d_in[0];
    const float* WD_w[2] = {(const float*)d_in[1], (const float*)d_in[9]};
    const float* WD_b[2] = {(const float*)d_in[2], (const float*)d_in[10]};
    const float* W1_w[2] = {(const float*)d_in[3], (const float*)d_in[11]};
    const float* W1_b[2] = {(const float*)d_in[4], (const float*)d_in[12]};
    const float* W2_w[2] = {(const float*)d_in[5], (const float*)d_in[13]};
    const float* W2_b[2] = {(const float*)d_in[6], (const float*)d_in[14]};
    const float* W3_w[2] = {(const float*)d_in[7], (const float*)d_in[15]};
    const float* W3_b[2] = {(const float*)d_in[8], (const float*)d_in[16]};
    const float* wih = (const float*)d_in[17];
    const float* whh = (const float*)d_in[18];
    const float* bih = (const float*)d_in[19];
    const float* bhh = (const float*)d_in[20];

    float* ws = (float*)d_ws;
    float* m1 = ws;                               // 4M floats
    float* m2 = m1 + (size_t)cM * cH;             // 4M
    float* us = m2 + (size_t)cM * cH;
    float* ue = us + cB * cD;
    float* h  = ue + cB * cD;
    float* c  = h + cB * cH;
    float* r  = c + cB * cH;
    float* rterm = r + cB * cH;                   // 64K
    float* cur = rterm + (size_t)cB * cN;

    ushort* m1h = (ushort*)cur;                   cur += (size_t)cM * cH / 2;
    ushort* m1l = (ushort*)cur;                   cur += (size_t)cM * cH / 2;
    ushort* Uh  = (ushort*)cur;                   cur += (size_t)cM * cD / 2;
    ushort* Ul  = (ushort*)cur;                   cur += (size_t)cM * cD / 2;
    ushort* W1th[2], *W1tl[2], *W2th[2], *W2tl[2];
    for (int sd = 0; sd < 2; ++sd) {
        W1th[sd] = (ushort*)cur; cur += (size_t)cN * cD / 2;   // [2048][256]
        W1tl[sd] = (ushort*)cur; cur += (size_t)cN * cD / 2;
        W2th[sd] = (ushort*)cur; cur += (size_t)cN * cH / 2;   // [2048][128]
        W2tl[sd] = (ushort*)cur; cur += (size_t)cN * cH / 2;
    }

    float* outf = (float*)d_out;

    init_kernel<<<32, 256, 0, stream>>>(U, us, ue, h, c);
    usplit_kernel<<<(cM * cD) / 256, 256, 0, stream>>>(U, Uh, Ul);
    for (int sd = 0; sd < 2; ++sd) {
        wsplit_kernel<<<(cD * cN) / 256, 256, 0, stream>>>(
            W1_w[sd], cD, cN, W1th[sd], W1tl[sd]);     // first 256 rows of W1
        wsplit_kernel<<<(cH * cN) / 256, 256, 0, stream>>>(
            W2_w[sd], cH, cN, W2th[sd], W2tl[sd]);
    }

    const int ggrid = (cN / 128) * (cM / 128);   // 4096
    for (int it = 0; it < 4; ++it) {
        for (int sd = 0; sd < 2; ++sd) {
            r_kernel<<<32, 128, 0, stream>>>(h, us, ue, WD_w[sd], WD_b[sd], r);
            rterm_kernel<<<dim3(8, 32), 256, 0, stream>>>(
                r, W1_w[sd] + (size_t)256 * cN, W1_b[sd], rterm);
            // m1 = pool(U @ W1[0:256] + rterm) — counted-vmcnt pipeline
            m1_pipe_kernel<<<ggrid, 256, 0, stream>>>(
                W1th[sd], W1tl[sd], Uh, Ul, rterm, m1, m1h, m1l);
            // m2 = pool(m1 @ W2 + b2) — r13 multi-subtile
            mfma_pool_m2<<<1024, 256, 0, stream>>>(
                W2th[sd], W2tl[sd], m1h, m1l, W2_b[sd], m2);
            float* ent = outf + 64 + (size_t)(it * 2 + sd) * cB * cT;
            score_kernel<<<2048, 256, 0, stream>>>(m1, m2, W3_w[sd], W3_b[sd], ent);
            argmax_kernel<<<32, 256, 0, stream>>>(ent, U, sd ? ue : us,
                                                  outf + (sd ? 32 : 0));
        }
        lstm_kernel<<<1024, 256, 0, stream>>>(us, ue, h, c, wih, whh, bih, bhh);
    }
}